// Round 7
// baseline (137.672 us; speedup 1.0000x reference)
//
#include <hip/hip_runtime.h>
#include <math.h>

#define B_BAGS 512
#define N_REL  128
#define D_DIM  768

typedef __attribute__((ext_vector_type(8))) short  bf16x8;
typedef __attribute__((ext_vector_type(4))) float  f32x4;

// pack truncated-bf16 of (f0,f1) -> one uint (low short = bf16(f0))
__device__ inline unsigned pack_hi(float f0, float f1) {
    return __builtin_amdgcn_perm(__float_as_uint(f1), __float_as_uint(f0), 0x07060302u);
}
__device__ inline float trunc_res(float f) {   // f - bf16_trunc(f)
    return f - __uint_as_float(__float_as_uint(f) & 0xFFFF0000u);
}

// ---------------------------------------------------------------------------
// Single fused kernel. 512 threads = 8 waves; wave T owns n-tile T (16 rels).
//  Phase 1: G-tile = bag @ W[T-tile]^T, bf16x3 MFMA. A rows from rep (global),
//           B packed on the fly from raw W (same element mapping as the
//           r2-r6-validated Bfrag: n = T*16+(lane&15), k = gs*32+(lane>>4)*8+j).
//           Register ring buffer, prefetch depth 2.
//  Softmax over m: in-register on C/D layout (xor 16/32) — r5/r6-validated.
//  Scatter G/SM hi+lo to frag layouts in LDS — r4-r6-validated formulas.
//  Phase 2: full-tile T = SM @ G (24 MFMA) + row softmax over k (xor 1/2/4/8)
//           + diagonal -> out — r6-validated verbatim.
// LDS = 32 KB, VGPR capped 128 -> 2 blocks/CU (16 waves/CU, 4 waves/SIMD).
// ---------------------------------------------------------------------------
__global__ __launch_bounds__(512, 4) void bag_fused(
    const float* __restrict__ rep,    // nsum x 768
    const float* __restrict__ W,      // 128 x 768
    const float* __restrict__ bias,   // 128
    const int*   __restrict__ scope,  // B x 2
    float*       __restrict__ out,    // B x 128
    int nsum)
{
    __shared__ unsigned Gfrag[8 * 2 * 64 * 4];    // 16 KB [tile][p][lane][4]
    __shared__ unsigned SMfrag[8 * 2 * 64 * 4];   // 16 KB

    const int t = threadIdx.x;
    const int b = blockIdx.x;
    const int start = scope[2 * b];
    const int size  = scope[2 * b + 1] - start;   // in [8, 25)

    const int wv   = t >> 6;      // 0..7 = owned n-tile T
    const int lane = t & 63;
    const int nl15 = lane & 15;
    const int lg   = lane >> 4;
    const int T    = wv;

    // ---- Phase 1 pointers ----
    const float* rpA[2];
    #pragma unroll
    for (int mt = 0; mt < 2; ++mt) {
        int row = start + mt * 16 + nl15;
        row = (row > nsum - 1) ? (nsum - 1) : row;   // clip like reference
        rpA[mt] = &rep[(size_t)row * D_DIM + lg * 8];
    }
    const float* rpB = &W[(size_t)(T * 16 + nl15) * D_DIM + lg * 8];

    f32x4 acc[2][2];   // [mt][0]=hi*hi, [1]=hi*lo+lo*hi
    #pragma unroll
    for (int mt = 0; mt < 2; ++mt) {
        acc[mt][0] = f32x4{0.f, 0.f, 0.f, 0.f};
        acc[mt][1] = f32x4{0.f, 0.f, 0.f, 0.f};
    }

    // ---- register ring buffer, prefetch depth 2 ----
    float4 bufA[2][4];   // [stage][mt*2 + half]
    float4 bufB[2][2];   // [stage][half]
    #pragma unroll
    for (int p = 0; p < 2; ++p) {
        #pragma unroll
        for (int mt = 0; mt < 2; ++mt) {
            bufA[p][mt * 2 + 0] = *(const float4*)&rpA[mt][p * 32];
            bufA[p][mt * 2 + 1] = *(const float4*)&rpA[mt][p * 32 + 4];
        }
        bufB[p][0] = *(const float4*)&rpB[p * 32];
        bufB[p][1] = *(const float4*)&rpB[p * 32 + 4];
    }

    #pragma unroll
    for (int gs = 0; gs < 24; ++gs) {
        const int st = gs & 1;
        // pull current stage into locals
        float4 a[4], w0, w1;
        #pragma unroll
        for (int i = 0; i < 4; ++i) a[i] = bufA[st][i];
        w0 = bufB[st][0];
        w1 = bufB[st][1];
        // prefetch gs+2 into this stage slot
        if (gs < 22) {
            #pragma unroll
            for (int mt = 0; mt < 2; ++mt) {
                bufA[st][mt * 2 + 0] = *(const float4*)&rpA[mt][(gs + 2) * 32];
                bufA[st][mt * 2 + 1] = *(const float4*)&rpA[mt][(gs + 2) * 32 + 4];
            }
            bufB[st][0] = *(const float4*)&rpB[(gs + 2) * 32];
            bufB[st][1] = *(const float4*)&rpB[(gs + 2) * 32 + 4];
        }

        // pack A (both m-tiles) and B -> bf16 hi/lo
        union { unsigned u[4]; bf16x8 v; } ah[2], al[2], bh, bl;
        #pragma unroll
        for (int mt = 0; mt < 2; ++mt) {
            const float4 v0 = a[mt * 2 + 0];
            const float4 v1 = a[mt * 2 + 1];
            ah[mt].u[0] = pack_hi(v0.x, v0.y);
            ah[mt].u[1] = pack_hi(v0.z, v0.w);
            ah[mt].u[2] = pack_hi(v1.x, v1.y);
            ah[mt].u[3] = pack_hi(v1.z, v1.w);
            al[mt].u[0] = pack_hi(trunc_res(v0.x), trunc_res(v0.y));
            al[mt].u[1] = pack_hi(trunc_res(v0.z), trunc_res(v0.w));
            al[mt].u[2] = pack_hi(trunc_res(v1.x), trunc_res(v1.y));
            al[mt].u[3] = pack_hi(trunc_res(v1.z), trunc_res(v1.w));
        }
        bh.u[0] = pack_hi(w0.x, w0.y);
        bh.u[1] = pack_hi(w0.z, w0.w);
        bh.u[2] = pack_hi(w1.x, w1.y);
        bh.u[3] = pack_hi(w1.z, w1.w);
        bl.u[0] = pack_hi(trunc_res(w0.x), trunc_res(w0.y));
        bl.u[1] = pack_hi(trunc_res(w0.z), trunc_res(w0.w));
        bl.u[2] = pack_hi(trunc_res(w1.x), trunc_res(w1.y));
        bl.u[3] = pack_hi(trunc_res(w1.z), trunc_res(w1.w));

        #pragma unroll
        for (int mt = 0; mt < 2; ++mt) {
            acc[mt][0] = __builtin_amdgcn_mfma_f32_16x16x32_bf16(ah[mt].v, bh.v, acc[mt][0], 0, 0, 0);
            acc[mt][1] = __builtin_amdgcn_mfma_f32_16x16x32_bf16(ah[mt].v, bl.v, acc[mt][1], 0, 0, 0);
            acc[mt][1] = __builtin_amdgcn_mfma_f32_16x16x32_bf16(al[mt].v, bh.v, acc[mt][1], 0, 0, 0);
        }
    }

    // ---- in-register masked softmax over m (validated r5/r6) ----
    // C/D layout: row m_local = lg*4 + r, col n_local = nl15.
    float gv[2][4], smv[2][4];
    #pragma unroll
    for (int mt = 0; mt < 2; ++mt)
        #pragma unroll
        for (int r = 0; r < 4; ++r)
            gv[mt][r] = acc[mt][0][r] + acc[mt][1][r];

    float vmax = -INFINITY;
    #pragma unroll
    for (int mt = 0; mt < 2; ++mt)
        #pragma unroll
        for (int r = 0; r < 4; ++r) {
            const int m = mt * 16 + lg * 4 + r;
            if (m < size) vmax = fmaxf(vmax, gv[mt][r]);
        }
    vmax = fmaxf(vmax, __shfl_xor(vmax, 16));
    vmax = fmaxf(vmax, __shfl_xor(vmax, 32));

    float ssum = 0.f;
    #pragma unroll
    for (int mt = 0; mt < 2; ++mt)
        #pragma unroll
        for (int r = 0; r < 4; ++r) {
            const int m = mt * 16 + lg * 4 + r;
            float e = (m < size) ? __expf(gv[mt][r] - vmax) : 0.f;
            smv[mt][r] = e;
            ssum += e;
        }
    ssum += __shfl_xor(ssum, 16);
    ssum += __shfl_xor(ssum, 32);
    const float inv = 1.f / ssum;
    #pragma unroll
    for (int mt = 0; mt < 2; ++mt)
        #pragma unroll
        for (int r = 0; r < 4; ++r) smv[mt][r] *= inv;

    // ---- scatter to frag layouts (validated r4-r6) ----
    // uint index = ((T*2 + p)*64 + (m>>3)*16 + nl15)*4 + ((m>>1)&3)
    #pragma unroll
    for (int mt = 0; mt < 2; ++mt)
        #pragma unroll
        for (int rp = 0; rp < 4; rp += 2) {
            const int m     = mt * 16 + lg * 4 + rp;
            const int lane2 = (m >> 3) * 16 + nl15;
            const int word  = (m >> 1) & 3;
            const int ihi = ((T * 2 + 0) * 64 + lane2) * 4 + word;
            const int ilo = ((T * 2 + 1) * 64 + lane2) * 4 + word;
            Gfrag[ihi]  = pack_hi(gv[mt][rp], gv[mt][rp + 1]);
            Gfrag[ilo]  = pack_hi(trunc_res(gv[mt][rp]), trunc_res(gv[mt][rp + 1]));
            SMfrag[ihi] = pack_hi(smv[mt][rp], smv[mt][rp + 1]);
            SMfrag[ilo] = pack_hi(trunc_res(smv[mt][rp]), trunc_res(smv[mt][rp + 1]));
        }
    __syncthreads();   // the only barrier

    // ---- Phase 2: row-tile T of full = SM @ G (validated r6) ----
    float bias_r[8];
    #pragma unroll
    for (int ct = 0; ct < 8; ++ct) bias_r[ct] = bias[ct * 16 + nl15];

    f32x4 facc[8];
    #pragma unroll
    for (int ct = 0; ct < 8; ++ct) facc[ct] = f32x4{0.f, 0.f, 0.f, 0.f};

    const bf16x8 ah2 = *(const bf16x8*)&SMfrag[((T * 2 + 0) * 64 + lane) * 4];
    const bf16x8 al2 = *(const bf16x8*)&SMfrag[((T * 2 + 1) * 64 + lane) * 4];
    #pragma unroll
    for (int ct = 0; ct < 8; ++ct) {
        const bf16x8 bh = *(const bf16x8*)&Gfrag[((ct * 2 + 0) * 64 + lane) * 4];
        const bf16x8 bl = *(const bf16x8*)&Gfrag[((ct * 2 + 1) * 64 + lane) * 4];
        facc[ct] = __builtin_amdgcn_mfma_f32_16x16x32_bf16(ah2, bh, facc[ct], 0, 0, 0);
        facc[ct] = __builtin_amdgcn_mfma_f32_16x16x32_bf16(ah2, bl, facc[ct], 0, 0, 0);
        facc[ct] = __builtin_amdgcn_mfma_f32_16x16x32_bf16(al2, bh, facc[ct], 0, 0, 0);
    }

    // ---- in-register row softmax over k + diagonal -> out (validated r6) ----
    // C/D layout: row n_local = lg*4 + r, col k = ct*16 + nl15.
    #pragma unroll
    for (int r = 0; r < 4; ++r) {
        float s[8];
        #pragma unroll
        for (int ct = 0; ct < 8; ++ct) s[ct] = facc[ct][r] + bias_r[ct];

        float mx = s[0];
        #pragma unroll
        for (int ct = 1; ct < 8; ++ct) mx = fmaxf(mx, s[ct]);
        mx = fmaxf(mx, __shfl_xor(mx, 1));
        mx = fmaxf(mx, __shfl_xor(mx, 2));
        mx = fmaxf(mx, __shfl_xor(mx, 4));
        mx = fmaxf(mx, __shfl_xor(mx, 8));

        float l = 0.f;
        #pragma unroll
        for (int ct = 0; ct < 8; ++ct) l += __expf(s[ct] - mx);
        l += __shfl_xor(l, 1);
        l += __shfl_xor(l, 2);
        l += __shfl_xor(l, 4);
        l += __shfl_xor(l, 8);

        const int nl = lg * 4 + r;               // row within tile
        float sd = s[0];
        #pragma unroll
        for (int ct = 1; ct < 8; ++ct) sd = (ct == T) ? s[ct] : sd;
        if (nl15 == nl) {
            out[b * N_REL + T * 16 + nl] = __expf(sd - mx) / l;
        }
    }
}

// ---------------------------------------------------------------------------
extern "C" void kernel_launch(void* const* d_in, const int* in_sizes, int n_in,
                              void* d_out, int out_size, void* d_ws, size_t ws_size,
                              hipStream_t stream) {
    const float* rep   = (const float*)d_in[0];
    const float* W     = (const float*)d_in[1];
    const float* bias  = (const float*)d_in[2];
    const int*   scope = (const int*)d_in[3];

    const int nsum = in_sizes[0] / D_DIM;

    bag_fused<<<B_BAGS, 512, 0, stream>>>(rep, W, bias, scope,
                                          (float*)d_out, nsum);
}

// Round 8
// 103.311 us; speedup vs baseline: 1.3326x; 1.3326x over previous
//
#include <hip/hip_runtime.h>
#include <math.h>

#define B_BAGS 512
#define N_REL  128
#define D_DIM  768

typedef __attribute__((ext_vector_type(8))) short  bf16x8;
typedef __attribute__((ext_vector_type(4))) float  f32x4;

// pack truncated-bf16 of (f0,f1) -> one uint (low short = bf16(f0))
__device__ inline unsigned pack_hi(float f0, float f1) {
    return __builtin_amdgcn_perm(__float_as_uint(f1), __float_as_uint(f0), 0x07060302u);
}
__device__ inline float trunc_res(float f) {   // f - bf16_trunc(f)
    return f - __uint_as_float(__float_as_uint(f) & 0xFFFF0000u);
}

// ---------------------------------------------------------------------------
// K1a: pre-pack rep into fragment-ordered bf16 hi/lo (Afrag).
// Layout (uints): Afrag[((grp*24 + gs)*2 + p)*256 + r*16 + jw]
//   element: row = grp*16 + r, k = gs*32 + jw*2 (+0/+1 within the uint)
// A-fragment for lane L of a 16x16x32 MFMA = uint4 at r=(L&15), jw=(L>>4)*4.
// ---------------------------------------------------------------------------
__global__ void afrag_prep(const float* __restrict__ rep,
                           unsigned* __restrict__ Afrag, int nsum) {
    const int grp = blockIdx.x;
    const int t   = threadIdx.x;
    #pragma unroll
    for (int i = 0; i < 24; ++i) {
        const int u   = i * 256 + t;          // 0..6143
        const int gs  = u >> 8;
        const int rem = u & 255;
        const int r   = rem >> 4;
        const int jw  = rem & 15;
        int row = grp * 16 + r;
        row = (row > nsum - 1) ? (nsum - 1) : row;
        const float2 f = *(const float2*)&rep[(size_t)row * D_DIM + gs * 32 + jw * 2];
        const unsigned base = (unsigned)((grp * 24 + gs) * 2) * 256 + rem;
        Afrag[base]       = pack_hi(f.x, f.y);
        Afrag[base + 256] = pack_hi(trunc_res(f.x), trunc_res(f.y));
    }
}

// ---------------------------------------------------------------------------
// K1b: fragment-ordered bf16 hi/lo of W (validated r2-r7).
// Element = W[n][k], n = tile*16 + (lane&15), k = s*32 + (lane>>4)*8 + j.
// ---------------------------------------------------------------------------
__global__ void build_bfrag(const float* __restrict__ W, unsigned* __restrict__ Bfrag) {
    int flat = blockIdx.x * 256 + threadIdx.x;     // 0..12287
    int lane = flat & 63;
    int tile = (flat >> 6) & 7;
    int s    = flat >> 9;                          // 0..23
    int n  = tile * 16 + (lane & 15);
    int k0 = s * 32 + (lane >> 4) * 8;
    const float* src = &W[n * D_DIM + k0];
    float f[8];
    #pragma unroll
    for (int j = 0; j < 8; ++j) f[j] = src[j];
    unsigned hi[4], lo[4];
    #pragma unroll
    for (int q = 0; q < 4; ++q) {
        hi[q] = pack_hi(f[2*q], f[2*q+1]);
        lo[q] = pack_hi(trunc_res(f[2*q]), trunc_res(f[2*q+1]));
    }
    unsigned base = (unsigned)(((s * 8 + tile) * 2) * 64 + lane) * 4;
    *(uint4*)&Bfrag[base]          = make_uint4(hi[0], hi[1], hi[2], hi[3]);
    *(uint4*)&Bfrag[base + 64 * 4] = make_uint4(lo[0], lo[1], lo[2], lo[3]);
}

// ---------------------------------------------------------------------------
// K2: fused per-bag kernel (R6 structure), all operands pre-packed.
//  Phase 1: wave (h = wv>>2, q = wv&3) computes K-half h of n-tiles {2q,2q+1}
//           via bf16x3 MFMA. A and B fragments are single contiguous uint4
//           loads from Afrag / Bfrag — zero pack VALU in the loop.
//  Partials merged via LDS Gpart (r6-validated); softmax over m in-register
//  (xor 16/32); scatter to frag layouts (r4-r7-validated); phase 2 = SM@G
//  24 MFMA + row softmax over k (xor 1/2/4/8) + diag -> out (r6 verbatim).
// ---------------------------------------------------------------------------
__global__ __launch_bounds__(512, 4) void bag_fused(
    const unsigned* __restrict__ Afrag,   // fragment-ordered rep hi/lo
    const unsigned* __restrict__ Bfrag,   // fragment-ordered W hi/lo
    const float*    __restrict__ bias,    // 128
    const int*      __restrict__ scope,   // B x 2
    float*          __restrict__ out,     // B x 128
    int nsum)
{
    __shared__ f32x4    Gpart[2][2][8][64];       // [h][mt][nt][lane]  32 KB
    __shared__ unsigned Gfrag[8 * 2 * 64 * 4];    // 16 KB [tile][p][lane][4]
    __shared__ unsigned SMfrag[8 * 2 * 64 * 4];   // 16 KB

    const int t = threadIdx.x;
    const int b = blockIdx.x;
    const int start = scope[2 * b];
    const int size  = scope[2 * b + 1] - start;   // in [8, 25)

    const int wv   = t >> 6;
    const int lane = t & 63;
    const int nl15 = lane & 15;
    const int lg   = lane >> 4;
    const int h    = wv >> 2;    // K-half (gs 0..11 or 12..23)
    const int q    = wv & 3;     // n-tile pair {2q, 2q+1}

    // ---- per-lane Afrag base addresses (loop-invariant) ----
    // addr(mt,p,gs) = ((grp*24 + gs)*2 + p)*256 + r*16 + lg*4
    unsigned abase[2][2];
    #pragma unroll
    for (int mt = 0; mt < 2; ++mt) {
        int row = start + mt * 16 + nl15;
        row = (row > nsum - 1) ? (nsum - 1) : row;   // clip like reference
        const unsigned grp = (unsigned)row >> 4;
        const unsigned r   = (unsigned)row & 15;
        #pragma unroll
        for (int p = 0; p < 2; ++p)
            abase[mt][p] = ((grp * 24 + h * 12) * 2 + p) * 256 + r * 16 + lg * 4;
    }
    // Bfrag base: addr(ntl,p,gs) = ((gs*8 + q*2+ntl)*2 + p)*256 + lane*4
    unsigned bbase[2][2];
    #pragma unroll
    for (int ntl = 0; ntl < 2; ++ntl)
        #pragma unroll
        for (int p = 0; p < 2; ++p)
            bbase[ntl][p] = (((h * 12) * 8 + q * 2 + ntl) * 2 + p) * 256 + lane * 4;

    f32x4 acc[2][2][2];   // [mt][ntl][0]=hi*hi, [1]=hi*lo+lo*hi
    #pragma unroll
    for (int mt = 0; mt < 2; ++mt)
        #pragma unroll
        for (int ntl = 0; ntl < 2; ++ntl) {
            acc[mt][ntl][0] = f32x4{0.f, 0.f, 0.f, 0.f};
            acc[mt][ntl][1] = f32x4{0.f, 0.f, 0.f, 0.f};
        }

    #pragma unroll
    for (int s = 0; s < 12; ++s) {
        bf16x8 ah[2], al[2], bh[2], bl[2];
        #pragma unroll
        for (int mt = 0; mt < 2; ++mt) {
            ah[mt] = *(const bf16x8*)&Afrag[abase[mt][0] + s * 512];
            al[mt] = *(const bf16x8*)&Afrag[abase[mt][1] + s * 512];
        }
        #pragma unroll
        for (int ntl = 0; ntl < 2; ++ntl) {
            bh[ntl] = *(const bf16x8*)&Bfrag[bbase[ntl][0] + s * 4096];
            bl[ntl] = *(const bf16x8*)&Bfrag[bbase[ntl][1] + s * 4096];
        }
        #pragma unroll
        for (int ntl = 0; ntl < 2; ++ntl)
            #pragma unroll
            for (int mt = 0; mt < 2; ++mt) {
                acc[mt][ntl][0] = __builtin_amdgcn_mfma_f32_16x16x32_bf16(ah[mt], bh[ntl], acc[mt][ntl][0], 0, 0, 0);
                acc[mt][ntl][1] = __builtin_amdgcn_mfma_f32_16x16x32_bf16(ah[mt], bl[ntl], acc[mt][ntl][1], 0, 0, 0);
                acc[mt][ntl][1] = __builtin_amdgcn_mfma_f32_16x16x32_bf16(al[mt], bh[ntl], acc[mt][ntl][1], 0, 0, 0);
            }
    }

    // ---- write K-half partials to LDS (r6-validated) ----
    #pragma unroll
    for (int mt = 0; mt < 2; ++mt)
        #pragma unroll
        for (int ntl = 0; ntl < 2; ++ntl)
            Gpart[h][mt][q * 2 + ntl][lane] = acc[mt][ntl][0] + acc[mt][ntl][1];
    __syncthreads();

    // ---- in-register masked softmax over m for n-tile T = wv ----
    // C/D layout: row m_local = lg*4 + r, col n_local = nl15.
    const int T = wv;
    float gv[2][4], smv[2][4];
    #pragma unroll
    for (int mt = 0; mt < 2; ++mt) {
        const f32x4 p0 = Gpart[0][mt][T][lane];
        const f32x4 p1 = Gpart[1][mt][T][lane];
        #pragma unroll
        for (int r = 0; r < 4; ++r) gv[mt][r] = p0[r] + p1[r];
    }

    float vmax = -INFINITY;
    #pragma unroll
    for (int mt = 0; mt < 2; ++mt)
        #pragma unroll
        for (int r = 0; r < 4; ++r) {
            const int m = mt * 16 + lg * 4 + r;
            if (m < size) vmax = fmaxf(vmax, gv[mt][r]);
        }
    vmax = fmaxf(vmax, __shfl_xor(vmax, 16));
    vmax = fmaxf(vmax, __shfl_xor(vmax, 32));

    float ssum = 0.f;
    #pragma unroll
    for (int mt = 0; mt < 2; ++mt)
        #pragma unroll
        for (int r = 0; r < 4; ++r) {
            const int m = mt * 16 + lg * 4 + r;
            float e = (m < size) ? __expf(gv[mt][r] - vmax) : 0.f;
            smv[mt][r] = e;
            ssum += e;
        }
    ssum += __shfl_xor(ssum, 16);
    ssum += __shfl_xor(ssum, 32);
    const float inv = 1.f / ssum;
    #pragma unroll
    for (int mt = 0; mt < 2; ++mt)
        #pragma unroll
        for (int r = 0; r < 4; ++r) smv[mt][r] *= inv;

    // ---- scatter to frag layouts (validated r4-r7) ----
    // uint index = ((T*2 + p)*64 + (m>>3)*16 + nl15)*4 + ((m>>1)&3)
    #pragma unroll
    for (int mt = 0; mt < 2; ++mt)
        #pragma unroll
        for (int rp = 0; rp < 4; rp += 2) {
            const int m     = mt * 16 + lg * 4 + rp;
            const int lane2 = (m >> 3) * 16 + nl15;
            const int word  = (m >> 1) & 3;
            const int ihi = ((T * 2 + 0) * 64 + lane2) * 4 + word;
            const int ilo = ((T * 2 + 1) * 64 + lane2) * 4 + word;
            Gfrag[ihi]  = pack_hi(gv[mt][rp], gv[mt][rp + 1]);
            Gfrag[ilo]  = pack_hi(trunc_res(gv[mt][rp]), trunc_res(gv[mt][rp + 1]));
            SMfrag[ihi] = pack_hi(smv[mt][rp], smv[mt][rp + 1]);
            SMfrag[ilo] = pack_hi(trunc_res(smv[mt][rp]), trunc_res(smv[mt][rp + 1]));
        }
    __syncthreads();

    // ---- Phase 2: row-tile T of full = SM @ G (validated r6) ----
    float bias_r[8];
    #pragma unroll
    for (int ct = 0; ct < 8; ++ct) bias_r[ct] = bias[ct * 16 + nl15];

    f32x4 facc[8];
    #pragma unroll
    for (int ct = 0; ct < 8; ++ct) facc[ct] = f32x4{0.f, 0.f, 0.f, 0.f};

    const bf16x8 ah2 = *(const bf16x8*)&SMfrag[((T * 2 + 0) * 64 + lane) * 4];
    const bf16x8 al2 = *(const bf16x8*)&SMfrag[((T * 2 + 1) * 64 + lane) * 4];
    #pragma unroll
    for (int ct = 0; ct < 8; ++ct) {
        const bf16x8 bh = *(const bf16x8*)&Gfrag[((ct * 2 + 0) * 64 + lane) * 4];
        const bf16x8 bl = *(const bf16x8*)&Gfrag[((ct * 2 + 1) * 64 + lane) * 4];
        facc[ct] = __builtin_amdgcn_mfma_f32_16x16x32_bf16(ah2, bh, facc[ct], 0, 0, 0);
        facc[ct] = __builtin_amdgcn_mfma_f32_16x16x32_bf16(ah2, bl, facc[ct], 0, 0, 0);
        facc[ct] = __builtin_amdgcn_mfma_f32_16x16x32_bf16(al2, bh, facc[ct], 0, 0, 0);
    }

    // ---- in-register row softmax over k + diagonal -> out (validated r6) ----
    // C/D layout: row n_local = lg*4 + r, col k = ct*16 + nl15.
    #pragma unroll
    for (int r = 0; r < 4; ++r) {
        float s[8];
        #pragma unroll
        for (int ct = 0; ct < 8; ++ct) s[ct] = facc[ct][r] + bias_r[ct];

        float mx = s[0];
        #pragma unroll
        for (int ct = 1; ct < 8; ++ct) mx = fmaxf(mx, s[ct]);
        mx = fmaxf(mx, __shfl_xor(mx, 1));
        mx = fmaxf(mx, __shfl_xor(mx, 2));
        mx = fmaxf(mx, __shfl_xor(mx, 4));
        mx = fmaxf(mx, __shfl_xor(mx, 8));

        float l = 0.f;
        #pragma unroll
        for (int ct = 0; ct < 8; ++ct) l += __expf(s[ct] - mx);
        l += __shfl_xor(l, 1);
        l += __shfl_xor(l, 2);
        l += __shfl_xor(l, 4);
        l += __shfl_xor(l, 8);

        const int nl = lg * 4 + r;               // row within tile
        float sd = s[0];
        #pragma unroll
        for (int ct = 1; ct < 8; ++ct) sd = (ct == T) ? s[ct] : sd;
        if (nl15 == nl) {
            out[b * N_REL + T * 16 + nl] = __expf(sd - mx) / l;
        }
    }
}

// ---------------------------------------------------------------------------
extern "C" void kernel_launch(void* const* d_in, const int* in_sizes, int n_in,
                              void* d_out, int out_size, void* d_ws, size_t ws_size,
                              hipStream_t stream) {
    const float* rep   = (const float*)d_in[0];
    const float* W     = (const float*)d_in[1];
    const float* bias  = (const float*)d_in[2];
    const int*   scope = (const int*)d_in[3];

    const int nsum   = in_sizes[0] / D_DIM;
    const int groups = (nsum + 15) >> 4;

    unsigned* Bfrag = (unsigned*)d_ws;                       // 393216 B
    unsigned* Afrag = (unsigned*)((char*)d_ws + 393216);     // groups*48 KB

    build_bfrag<<<48, 256, 0, stream>>>(W, Bfrag);
    afrag_prep<<<groups, 256, 0, stream>>>(rep, Afrag, nsum);
    bag_fused<<<B_BAGS, 512, 0, stream>>>(Afrag, Bfrag, bias, scope,
                                          (float*)d_out, nsum);
}

// Round 9
// 100.920 us; speedup vs baseline: 1.3642x; 1.0237x over previous
//
#include <hip/hip_runtime.h>
#include <math.h>

#define B_BAGS 512
#define N_REL  128
#define D_DIM  768
#define NCHUNK 4       // split-K chunks (6 gs each)

typedef __attribute__((ext_vector_type(8))) short  bf16x8;
typedef __attribute__((ext_vector_type(4))) float  f32x4;

// pack truncated-bf16 of (f0,f1) -> one uint (low short = bf16(f0))
__device__ inline unsigned pack_hi(float f0, float f1) {
    return __builtin_amdgcn_perm(__float_as_uint(f1), __float_as_uint(f0), 0x07060302u);
}
__device__ inline float trunc_res(float f) {   // f - bf16_trunc(f)
    return f - __uint_as_float(__float_as_uint(f) & 0xFFFF0000u);
}

// ---------------------------------------------------------------------------
// K1: fragment-ordered bf16 hi/lo of W (validated r2-r8).
// uint index = ((s*8 + tile)*2 + p)*256 + lane*4 + 0..3
// Element: n = tile*16 + (lane&15), k = s*32 + (lane>>4)*8 + j.
// ---------------------------------------------------------------------------
__global__ void build_bfrag(const float* __restrict__ W, unsigned* __restrict__ Bfrag) {
    int flat = blockIdx.x * 256 + threadIdx.x;     // 0..12287
    int lane = flat & 63;
    int tile = (flat >> 6) & 7;
    int s    = flat >> 9;                          // 0..23
    int n  = tile * 16 + (lane & 15);
    int k0 = s * 32 + (lane >> 4) * 8;
    const float* src = &W[n * D_DIM + k0];
    float f[8];
    #pragma unroll
    for (int j = 0; j < 8; ++j) f[j] = src[j];
    unsigned hi[4], lo[4];
    #pragma unroll
    for (int q = 0; q < 4; ++q) {
        hi[q] = pack_hi(f[2*q], f[2*q+1]);
        lo[q] = pack_hi(trunc_res(f[2*q]), trunc_res(f[2*q+1]));
    }
    unsigned base = (unsigned)(((s * 8 + tile) * 2) * 64 + lane) * 4;
    *(uint4*)&Bfrag[base]          = make_uint4(hi[0], hi[1], hi[2], hi[3]);
    *(uint4*)&Bfrag[base + 64 * 4] = make_uint4(lo[0], lo[1], lo[2], lo[3]);
}

// ---------------------------------------------------------------------------
// K2: dense split-K H = rep @ W^T. grid (strips, NCHUNK), 512 thr = 8 waves.
// Block (strip, chunk): rows strip*128..+128, K-slice chunk*192..+192 (6 gs).
// Wave (j = wv&3, nh = wv>>2): m-tiles {2j,2j+1} (32 rows) x n-tiles nh*4..+4.
// A: fp32 staged to LDS as packed bf16 hi/lo per 64-k stage (3 stages),
//    padded stride 36 uints -> conflict-free ds_read_b128 fragments.
// B: direct global uint4 loads from L2-resident Bfrag (validated layout).
// Output: plain stores to partial buffer Hp[chunk] (no atomics, no memset).
// ---------------------------------------------------------------------------
__global__ __launch_bounds__(512, 2) void h_gemm(
    const float*    __restrict__ rep,
    const unsigned* __restrict__ Bfrag,
    float*          __restrict__ Hp,     // NCHUNK buffers of hstride floats
    int nsum, int hstride)
{
    __shared__ unsigned As[2 * 128 * 36];   // [p][row][36 uints]  36 KB

    const int t     = threadIdx.x;
    const int strip = blockIdx.x;
    const int chunk = blockIdx.y;

    const int wv   = t >> 6;
    const int lane = t & 63;
    const int nl15 = lane & 15;
    const int lg   = lane >> 4;
    const int j    = wv & 3;     // m-tile pair {2j, 2j+1}
    const int nh   = wv >> 2;    // n-tile quad nh*4..+4

    // staging indices: thread covers row t>>2, cols (t&3)*16..+16 of the stage
    const int srow = t >> 2;
    const int scq  = t & 3;
    int grow = strip * 128 + srow;
    grow = (grow > nsum - 1) ? (nsum - 1) : grow;
    const float* srp = &rep[(size_t)grow * D_DIM + chunk * 192 + scq * 16];

    f32x4 acc[2][4][2];   // [mt][i][0]=hi*hi, [1]=hi*lo+lo*hi
    #pragma unroll
    for (int mt = 0; mt < 2; ++mt)
        #pragma unroll
        for (int i = 0; i < 4; ++i) {
            acc[mt][i][0] = f32x4{0.f, 0.f, 0.f, 0.f};
            acc[mt][i][1] = f32x4{0.f, 0.f, 0.f, 0.f};
        }

    // A-fragment LDS read offsets (uints): (p*128 + row)*36 + g*16 + lg*4
    unsigned afo[2][2];
    #pragma unroll
    for (int mt = 0; mt < 2; ++mt) {
        const int row = (j * 2 + mt) * 16 + nl15;
        afo[mt][0] = (0 * 128 + row) * 36 + lg * 4;
        afo[mt][1] = (1 * 128 + row) * 36 + lg * 4;
    }

    #pragma unroll
    for (int st = 0; st < 3; ++st) {
        if (st) __syncthreads();    // previous stage's reads complete
        // ---- stage 64 k-columns: fp32 -> bf16 hi/lo into LDS ----
        {
            const float4 v0 = *(const float4*)&srp[st * 64];
            const float4 v1 = *(const float4*)&srp[st * 64 + 4];
            const float4 v2 = *(const float4*)&srp[st * 64 + 8];
            const float4 v3 = *(const float4*)&srp[st * 64 + 12];
            unsigned hi[8], lo[8];
            const float f[16] = {v0.x,v0.y,v0.z,v0.w, v1.x,v1.y,v1.z,v1.w,
                                 v2.x,v2.y,v2.z,v2.w, v3.x,v3.y,v3.z,v3.w};
            #pragma unroll
            for (int w = 0; w < 8; ++w) {
                hi[w] = pack_hi(f[2*w], f[2*w+1]);
                lo[w] = pack_hi(trunc_res(f[2*w]), trunc_res(f[2*w+1]));
            }
            const unsigned bh = (0 * 128 + srow) * 36 + scq * 8;
            const unsigned bl = (1 * 128 + srow) * 36 + scq * 8;
            *(uint4*)&As[bh]     = make_uint4(hi[0], hi[1], hi[2], hi[3]);
            *(uint4*)&As[bh + 4] = make_uint4(hi[4], hi[5], hi[6], hi[7]);
            *(uint4*)&As[bl]     = make_uint4(lo[0], lo[1], lo[2], lo[3]);
            *(uint4*)&As[bl + 4] = make_uint4(lo[4], lo[5], lo[6], lo[7]);
        }
        __syncthreads();

        // ---- compute 2 gs of this stage ----
        #pragma unroll
        for (int g = 0; g < 2; ++g) {
            const int gsg = chunk * 6 + st * 2 + g;   // global K-step
            bf16x8 ah[2], al[2];
            #pragma unroll
            for (int mt = 0; mt < 2; ++mt) {
                ah[mt] = *(const bf16x8*)&As[afo[mt][0] + g * 16];
                al[mt] = *(const bf16x8*)&As[afo[mt][1] + g * 16];
            }
            #pragma unroll
            for (int i = 0; i < 4; ++i) {
                const int nt = nh * 4 + i;
                const bf16x8 bh = *(const bf16x8*)&Bfrag[((gsg * 8 + nt) * 2 + 0) * 256 + lane * 4];
                const bf16x8 bl = *(const bf16x8*)&Bfrag[((gsg * 8 + nt) * 2 + 1) * 256 + lane * 4];
                #pragma unroll
                for (int mt = 0; mt < 2; ++mt) {
                    acc[mt][i][0] = __builtin_amdgcn_mfma_f32_16x16x32_bf16(ah[mt], bh, acc[mt][i][0], 0, 0, 0);
                    acc[mt][i][1] = __builtin_amdgcn_mfma_f32_16x16x32_bf16(ah[mt], bl, acc[mt][i][1], 0, 0, 0);
                    acc[mt][i][1] = __builtin_amdgcn_mfma_f32_16x16x32_bf16(al[mt], bh, acc[mt][i][1], 0, 0, 0);
                }
            }
        }
    }

    // ---- epilogue: C/D layout col=lane&15, row=(lane>>4)*4+r (validated) ----
    float* H = Hp + (size_t)chunk * hstride;
    #pragma unroll
    for (int mt = 0; mt < 2; ++mt) {
        const int rowb = strip * 128 + (j * 2 + mt) * 16 + lg * 4;
        #pragma unroll
        for (int i = 0; i < 4; ++i) {
            const int col = (nh * 4 + i) * 16 + nl15;
            #pragma unroll
            for (int r = 0; r < 4; ++r)
                H[(size_t)(rowb + r) * N_REL + col] = acc[mt][i][0][r] + acc[mt][i][1][r];
        }
    }
}

// ---------------------------------------------------------------------------
// K3: per-bag output. 512 thr = 8 waves; wave T = wv owns n-tile T.
// gv loaded directly from the 4 Hp partials into C/D-register positions,
// then the r5-r8-validated tail: in-register masked softmax over m,
// frag scatter, 24-MFMA phase 2, in-register row softmax over k, diag -> out.
// ---------------------------------------------------------------------------
__global__ __launch_bounds__(512, 2) void bag_out(
    const float* __restrict__ Hp, int hstride,
    const float* __restrict__ bias,
    const int*   __restrict__ scope,
    float*       __restrict__ out,
    int nsum)
{
    __shared__ unsigned Gfrag[8 * 2 * 64 * 4];    // 16 KB [tile][p][lane][4]
    __shared__ unsigned SMfrag[8 * 2 * 64 * 4];   // 16 KB

    const int t = threadIdx.x;
    const int b = blockIdx.x;
    const int start = scope[2 * b];
    const int size  = scope[2 * b + 1] - start;   // in [8, 25)

    const int wv   = t >> 6;
    const int lane = t & 63;
    const int nl15 = lane & 15;
    const int lg   = lane >> 4;
    const int T    = wv;

    // ---- gv: sum of 4 partials, loaded in C/D positions ----
    // m = mt*16 + lg*4 + r, col n = T*16 + nl15
    float gv[2][4], smv[2][4];
    #pragma unroll
    for (int mt = 0; mt < 2; ++mt)
        #pragma unroll
        for (int r = 0; r < 4; ++r) {
            int row = start + mt * 16 + lg * 4 + r;
            row = (row > nsum - 1) ? (nsum - 1) : row;   // pad rows: masked later
            const float* p = &Hp[(size_t)row * N_REL + T * 16 + nl15];
            gv[mt][r] = p[0] + p[(size_t)hstride] + p[(size_t)hstride * 2]
                             + p[(size_t)hstride * 3];
        }

    // ---- in-register masked softmax over m (validated r5-r8) ----
    float vmax = -INFINITY;
    #pragma unroll
    for (int mt = 0; mt < 2; ++mt)
        #pragma unroll
        for (int r = 0; r < 4; ++r) {
            const int m = mt * 16 + lg * 4 + r;
            if (m < size) vmax = fmaxf(vmax, gv[mt][r]);
        }
    vmax = fmaxf(vmax, __shfl_xor(vmax, 16));
    vmax = fmaxf(vmax, __shfl_xor(vmax, 32));

    float ssum = 0.f;
    #pragma unroll
    for (int mt = 0; mt < 2; ++mt)
        #pragma unroll
        for (int r = 0; r < 4; ++r) {
            const int m = mt * 16 + lg * 4 + r;
            float e = (m < size) ? __expf(gv[mt][r] - vmax) : 0.f;
            smv[mt][r] = e;
            ssum += e;
        }
    ssum += __shfl_xor(ssum, 16);
    ssum += __shfl_xor(ssum, 32);
    const float inv = 1.f / ssum;
    #pragma unroll
    for (int mt = 0; mt < 2; ++mt)
        #pragma unroll
        for (int r = 0; r < 4; ++r) smv[mt][r] *= inv;

    // ---- scatter to frag layouts (validated r4-r8) ----
    #pragma unroll
    for (int mt = 0; mt < 2; ++mt)
        #pragma unroll
        for (int rp = 0; rp < 4; rp += 2) {
            const int m     = mt * 16 + lg * 4 + rp;
            const int lane2 = (m >> 3) * 16 + nl15;
            const int word  = (m >> 1) & 3;
            const int ihi = ((T * 2 + 0) * 64 + lane2) * 4 + word;
            const int ilo = ((T * 2 + 1) * 64 + lane2) * 4 + word;
            Gfrag[ihi]  = pack_hi(gv[mt][rp], gv[mt][rp + 1]);
            Gfrag[ilo]  = pack_hi(trunc_res(gv[mt][rp]), trunc_res(gv[mt][rp + 1]));
            SMfrag[ihi] = pack_hi(smv[mt][rp], smv[mt][rp + 1]);
            SMfrag[ilo] = pack_hi(trunc_res(smv[mt][rp]), trunc_res(smv[mt][rp + 1]));
        }
    __syncthreads();   // the only barrier

    // ---- Phase 2: row-tile T of full = SM @ G (validated r6-r8) ----
    float bias_r[8];
    #pragma unroll
    for (int ct = 0; ct < 8; ++ct) bias_r[ct] = bias[ct * 16 + nl15];

    f32x4 facc[8];
    #pragma unroll
    for (int ct = 0; ct < 8; ++ct) facc[ct] = f32x4{0.f, 0.f, 0.f, 0.f};

    const bf16x8 ah2 = *(const bf16x8*)&SMfrag[((T * 2 + 0) * 64 + lane) * 4];
    const bf16x8 al2 = *(const bf16x8*)&SMfrag[((T * 2 + 1) * 64 + lane) * 4];
    #pragma unroll
    for (int ct = 0; ct < 8; ++ct) {
        const bf16x8 bh = *(const bf16x8*)&Gfrag[((ct * 2 + 0) * 64 + lane) * 4];
        const bf16x8 bl = *(const bf16x8*)&Gfrag[((ct * 2 + 1) * 64 + lane) * 4];
        facc[ct] = __builtin_amdgcn_mfma_f32_16x16x32_bf16(ah2, bh, facc[ct], 0, 0, 0);
        facc[ct] = __builtin_amdgcn_mfma_f32_16x16x32_bf16(ah2, bl, facc[ct], 0, 0, 0);
        facc[ct] = __builtin_amdgcn_mfma_f32_16x16x32_bf16(al2, bh, facc[ct], 0, 0, 0);
    }

    // ---- in-register row softmax over k + diagonal -> out (validated r6-r8) --
    #pragma unroll
    for (int r = 0; r < 4; ++r) {
        float s[8];
        #pragma unroll
        for (int ct = 0; ct < 8; ++ct) s[ct] = facc[ct][r] + bias_r[ct];

        float mx = s[0];
        #pragma unroll
        for (int ct = 1; ct < 8; ++ct) mx = fmaxf(mx, s[ct]);
        mx = fmaxf(mx, __shfl_xor(mx, 1));
        mx = fmaxf(mx, __shfl_xor(mx, 2));
        mx = fmaxf(mx, __shfl_xor(mx, 4));
        mx = fmaxf(mx, __shfl_xor(mx, 8));

        float l = 0.f;
        #pragma unroll
        for (int ct = 0; ct < 8; ++ct) l += __expf(s[ct] - mx);
        l += __shfl_xor(l, 1);
        l += __shfl_xor(l, 2);
        l += __shfl_xor(l, 4);
        l += __shfl_xor(l, 8);

        const int nl = lg * 4 + r;
        float sd = s[0];
        #pragma unroll
        for (int ct = 1; ct < 8; ++ct) sd = (ct == T) ? s[ct] : sd;
        if (nl15 == nl) {
            out[b * N_REL + T * 16 + nl] = __expf(sd - mx) / l;
        }
    }
}

// ---------------------------------------------------------------------------
extern "C" void kernel_launch(void* const* d_in, const int* in_sizes, int n_in,
                              void* d_out, int out_size, void* d_ws, size_t ws_size,
                              hipStream_t stream) {
    const float* rep   = (const float*)d_in[0];
    const float* W     = (const float*)d_in[1];
    const float* bias  = (const float*)d_in[2];
    const int*   scope = (const int*)d_in[3];

    const int nsum    = in_sizes[0] / D_DIM;
    const int strips  = (nsum + 127) >> 7;
    const int hstride = strips * 128 * N_REL;    // floats per partial buffer

    unsigned* Bfrag = (unsigned*)d_ws;                       // 393216 B
    float*    Hp    = (float*)((char*)d_ws + 393216);        // NCHUNK * hstride

    build_bfrag<<<48, 256, 0, stream>>>(W, Bfrag);
    h_gemm<<<dim3(strips, NCHUNK), 512, 0, stream>>>(rep, Bfrag, Hp, nsum, hstride);
    bag_out<<<B_BAGS, 512, 0, stream>>>(Hp, hstride, bias, scope,
                                        (float*)d_out, nsum);
}

// Round 10
// 97.529 us; speedup vs baseline: 1.4116x; 1.0348x over previous
//
#include <hip/hip_runtime.h>
#include <math.h>

#define B_BAGS 512
#define N_REL  128
#define D_DIM  768

typedef __attribute__((ext_vector_type(8))) short  bf16x8;
typedef __attribute__((ext_vector_type(4))) float  f32x4;

// pack truncated-bf16 of (f0,f1) -> one uint (low short = bf16(f0))
__device__ inline unsigned pack_hi(float f0, float f1) {
    return __builtin_amdgcn_perm(__float_as_uint(f1), __float_as_uint(f0), 0x07060302u);
}
__device__ inline float trunc_res(float f) {   // f - bf16_trunc(f)
    return f - __uint_as_float(__float_as_uint(f) & 0xFFFF0000u);
}

// ---------------------------------------------------------------------------
// K1: fragment-ordered bf16 hi/lo of W (validated r2-r9).
// uint index = ((s*8 + tile)*2 + p)*256 + lane*4 + 0..3
// Element: n = tile*16 + (lane&15), k = s*32 + (lane>>4)*8 + j.
// ---------------------------------------------------------------------------
__global__ void build_bfrag(const float* __restrict__ W, unsigned* __restrict__ Bfrag) {
    int flat = blockIdx.x * 256 + threadIdx.x;     // 0..12287
    int lane = flat & 63;
    int tile = (flat >> 6) & 7;
    int s    = flat >> 9;                          // 0..23
    int n  = tile * 16 + (lane & 15);
    int k0 = s * 32 + (lane >> 4) * 8;
    const float* src = &W[n * D_DIM + k0];
    float f[8];
    #pragma unroll
    for (int j = 0; j < 8; ++j) f[j] = src[j];
    unsigned hi[4], lo[4];
    #pragma unroll
    for (int q = 0; q < 4; ++q) {
        hi[q] = pack_hi(f[2*q], f[2*q+1]);
        lo[q] = pack_hi(trunc_res(f[2*q]), trunc_res(f[2*q+1]));
    }
    unsigned base = (unsigned)(((s * 8 + tile) * 2) * 64 + lane) * 4;
    *(uint4*)&Bfrag[base]          = make_uint4(hi[0], hi[1], hi[2], hi[3]);
    *(uint4*)&Bfrag[base + 64 * 4] = make_uint4(lo[0], lo[1], lo[2], lo[3]);
}

// ---------------------------------------------------------------------------
// K2: dense FULL-K H = rep @ W^T. grid = strips of 32 rows (~256 blocks),
// 512 thr = 8 waves. Wave (mt = wv&1, nh = wv>>1): 16 rows x n-tiles
// {nh*2, nh*2+1}, all 768 of K. A staged per-128-k chunk into LDS as packed
// bf16 hi/lo (stride-68 pad, 2-way conflicts = free). B direct from
// L2-resident Bfrag (validated layout). Single H output, plain stores.
// ---------------------------------------------------------------------------
__global__ __launch_bounds__(512, 2) void h_gemm(
    const float*    __restrict__ rep,
    const unsigned* __restrict__ Bfrag,
    float*          __restrict__ H,
    int nsum)
{
    __shared__ unsigned As[2][32][68];   // [plane][row][64+4 pad]  17.4 KB

    const int t     = threadIdx.x;
    const int strip = blockIdx.x;

    const int wv   = t >> 6;
    const int lane = t & 63;
    const int nl15 = lane & 15;
    const int lg   = lane >> 4;
    const int mt   = wv & 1;     // m-tile (16 rows)
    const int nh   = wv >> 1;    // n-tile pair {nh*2, nh*2+1}

    // staging: thread covers row t>>4, 8 k-cols at (t&15)*8 of each chunk
    const int srow = t >> 4;
    const int scq  = t & 15;
    int grow = strip * 32 + srow;
    grow = (grow > nsum - 1) ? (nsum - 1) : grow;
    const float* srp = &rep[(size_t)grow * D_DIM + scq * 8];

    f32x4 acc[2][2];   // [ntl][0]=hi*hi, [1]=hi*lo+lo*hi
    #pragma unroll
    for (int ntl = 0; ntl < 2; ++ntl) {
        acc[ntl][0] = f32x4{0.f, 0.f, 0.f, 0.f};
        acc[ntl][1] = f32x4{0.f, 0.f, 0.f, 0.f};
    }

    const int arow = mt * 16 + nl15;    // A-fragment LDS row

    #pragma unroll
    for (int st = 0; st < 6; ++st) {
        if (st) __syncthreads();        // previous chunk's reads complete
        // ---- stage 128 k-cols: fp32 -> bf16 hi/lo into LDS ----
        {
            const float4 v0 = *(const float4*)&srp[st * 128];
            const float4 v1 = *(const float4*)&srp[st * 128 + 4];
            const float f[8] = {v0.x, v0.y, v0.z, v0.w, v1.x, v1.y, v1.z, v1.w};
            unsigned hi[4], lo[4];
            #pragma unroll
            for (int w = 0; w < 4; ++w) {
                hi[w] = pack_hi(f[2*w], f[2*w+1]);
                lo[w] = pack_hi(trunc_res(f[2*w]), trunc_res(f[2*w+1]));
            }
            *(uint4*)&As[0][srow][scq * 4] = make_uint4(hi[0], hi[1], hi[2], hi[3]);
            *(uint4*)&As[1][srow][scq * 4] = make_uint4(lo[0], lo[1], lo[2], lo[3]);
        }
        __syncthreads();

        // ---- compute 4 gs of this chunk ----
        #pragma unroll
        for (int g = 0; g < 4; ++g) {
            const int gs = st * 4 + g;                    // global K-step 0..23
            const bf16x8 ah = *(const bf16x8*)&As[0][arow][g * 16 + lg * 4];
            const bf16x8 al = *(const bf16x8*)&As[1][arow][g * 16 + lg * 4];
            #pragma unroll
            for (int ntl = 0; ntl < 2; ++ntl) {
                const int nt = nh * 2 + ntl;
                const bf16x8 bh = *(const bf16x8*)&Bfrag[((gs * 8 + nt) * 2 + 0) * 256 + lane * 4];
                const bf16x8 bl = *(const bf16x8*)&Bfrag[((gs * 8 + nt) * 2 + 1) * 256 + lane * 4];
                acc[ntl][0] = __builtin_amdgcn_mfma_f32_16x16x32_bf16(ah, bh, acc[ntl][0], 0, 0, 0);
                acc[ntl][1] = __builtin_amdgcn_mfma_f32_16x16x32_bf16(ah, bl, acc[ntl][1], 0, 0, 0);
                acc[ntl][1] = __builtin_amdgcn_mfma_f32_16x16x32_bf16(al, bh, acc[ntl][1], 0, 0, 0);
            }
        }
    }

    // ---- epilogue: C/D layout col=lane&15, row=(lane>>4)*4+r (validated) ----
    const int rowb = strip * 32 + mt * 16 + lg * 4;
    #pragma unroll
    for (int ntl = 0; ntl < 2; ++ntl) {
        const int col = (nh * 2 + ntl) * 16 + nl15;
        #pragma unroll
        for (int r = 0; r < 4; ++r)
            H[(size_t)(rowb + r) * N_REL + col] = acc[ntl][0][r] + acc[ntl][1][r];
    }
}

// ---------------------------------------------------------------------------
// K3: per-bag output. 512 thr = 8 waves; wave T = wv owns n-tile T.
// gv loaded directly from H in C/D-register positions (8 loads/thread),
// then the r5-r9-validated tail: in-register masked softmax over m,
// frag scatter, 24-MFMA phase 2, in-register row softmax over k, diag -> out.
// ---------------------------------------------------------------------------
__global__ __launch_bounds__(512, 2) void bag_out(
    const float* __restrict__ H,
    const float* __restrict__ bias,
    const int*   __restrict__ scope,
    float*       __restrict__ out,
    int nsum)
{
    __shared__ unsigned Gfrag[8 * 2 * 64 * 4];    // 16 KB [tile][p][lane][4]
    __shared__ unsigned SMfrag[8 * 2 * 64 * 4];   // 16 KB

    const int t = threadIdx.x;
    const int b = blockIdx.x;
    const int start = scope[2 * b];
    const int size  = scope[2 * b + 1] - start;   // in [8, 25)

    const int wv   = t >> 6;
    const int lane = t & 63;
    const int nl15 = lane & 15;
    const int lg   = lane >> 4;
    const int T    = wv;

    // ---- gv from H in C/D positions: m = mt*16 + lg*4 + r, n = T*16 + nl15 --
    float gv[2][4], smv[2][4];
    #pragma unroll
    for (int mt = 0; mt < 2; ++mt)
        #pragma unroll
        for (int r = 0; r < 4; ++r) {
            int row = start + mt * 16 + lg * 4 + r;
            row = (row > nsum - 1) ? (nsum - 1) : row;   // pad rows: masked later
            gv[mt][r] = H[(size_t)row * N_REL + T * 16 + nl15];
        }

    // ---- in-register masked softmax over m (validated r5-r9) ----
    float vmax = -INFINITY;
    #pragma unroll
    for (int mt = 0; mt < 2; ++mt)
        #pragma unroll
        for (int r = 0; r < 4; ++r) {
            const int m = mt * 16 + lg * 4 + r;
            if (m < size) vmax = fmaxf(vmax, gv[mt][r]);
        }
    vmax = fmaxf(vmax, __shfl_xor(vmax, 16));
    vmax = fmaxf(vmax, __shfl_xor(vmax, 32));

    float ssum = 0.f;
    #pragma unroll
    for (int mt = 0; mt < 2; ++mt)
        #pragma unroll
        for (int r = 0; r < 4; ++r) {
            const int m = mt * 16 + lg * 4 + r;
            float e = (m < size) ? __expf(gv[mt][r] - vmax) : 0.f;
            smv[mt][r] = e;
            ssum += e;
        }
    ssum += __shfl_xor(ssum, 16);
    ssum += __shfl_xor(ssum, 32);
    const float inv = 1.f / ssum;
    #pragma unroll
    for (int mt = 0; mt < 2; ++mt)
        #pragma unroll
        for (int r = 0; r < 4; ++r) smv[mt][r] *= inv;

    // ---- scatter to frag layouts (validated r4-r9) ----
    #pragma unroll
    for (int mt = 0; mt < 2; ++mt)
        #pragma unroll
        for (int rp = 0; rp < 4; rp += 2) {
            const int m     = mt * 16 + lg * 4 + rp;
            const int lane2 = (m >> 3) * 16 + nl15;
            const int word  = (m >> 1) & 3;
            const int ihi = ((T * 2 + 0) * 64 + lane2) * 4 + word;
            const int ilo = ((T * 2 + 1) * 64 + lane2) * 4 + word;
            Gfrag[ihi]  = pack_hi(gv[mt][rp], gv[mt][rp + 1]);
            Gfrag[ilo]  = pack_hi(trunc_res(gv[mt][rp]), trunc_res(gv[mt][rp + 1]));
            SMfrag[ihi] = pack_hi(smv[mt][rp], smv[mt][rp + 1]);
            SMfrag[ilo] = pack_hi(trunc_res(smv[mt][rp]), trunc_res(smv[mt][rp + 1]));
        }
    __syncthreads();   // the only barrier

    // ---- Phase 2: row-tile T of full = SM @ G (validated r6-r9) ----
    float bias_r[8];
    #pragma unroll
    for (int ct = 0; ct < 8; ++ct) bias_r[ct] = bias[ct * 16 + nl15];

    f32x4 facc[8];
    #pragma unroll
    for (int ct = 0; ct < 8; ++ct) facc[ct] = f32x4{0.f, 0.f, 0.f, 0.f};

    const bf16x8 ah2 = *(const bf16x8*)&SMfrag[((T * 2 + 0) * 64 + lane) * 4];
    const bf16x8 al2 = *(const bf16x8*)&SMfrag[((T * 2 + 1) * 64 + lane) * 4];
    #pragma unroll
    for (int ct = 0; ct < 8; ++ct) {
        const bf16x8 bh = *(const bf16x8*)&Gfrag[((ct * 2 + 0) * 64 + lane) * 4];
        const bf16x8 bl = *(const bf16x8*)&Gfrag[((ct * 2 + 1) * 64 + lane) * 4];
        facc[ct] = __builtin_amdgcn_mfma_f32_16x16x32_bf16(ah2, bh, facc[ct], 0, 0, 0);
        facc[ct] = __builtin_amdgcn_mfma_f32_16x16x32_bf16(ah2, bl, facc[ct], 0, 0, 0);
        facc[ct] = __builtin_amdgcn_mfma_f32_16x16x32_bf16(al2, bh, facc[ct], 0, 0, 0);
    }

    // ---- in-register row softmax over k + diagonal -> out (validated r6-r9) --
    #pragma unroll
    for (int r = 0; r < 4; ++r) {
        float s[8];
        #pragma unroll
        for (int ct = 0; ct < 8; ++ct) s[ct] = facc[ct][r] + bias_r[ct];

        float mx = s[0];
        #pragma unroll
        for (int ct = 1; ct < 8; ++ct) mx = fmaxf(mx, s[ct]);
        mx = fmaxf(mx, __shfl_xor(mx, 1));
        mx = fmaxf(mx, __shfl_xor(mx, 2));
        mx = fmaxf(mx, __shfl_xor(mx, 4));
        mx = fmaxf(mx, __shfl_xor(mx, 8));

        float l = 0.f;
        #pragma unroll
        for (int ct = 0; ct < 8; ++ct) l += __expf(s[ct] - mx);
        l += __shfl_xor(l, 1);
        l += __shfl_xor(l, 2);
        l += __shfl_xor(l, 4);
        l += __shfl_xor(l, 8);

        const int nl = lg * 4 + r;
        float sd = s[0];
        #pragma unroll
        for (int ct = 1; ct < 8; ++ct) sd = (ct == T) ? s[ct] : sd;
        if (nl15 == nl) {
            out[b * N_REL + T * 16 + nl] = __expf(sd - mx) / l;
        }
    }
}

// ---------------------------------------------------------------------------
extern "C" void kernel_launch(void* const* d_in, const int* in_sizes, int n_in,
                              void* d_out, int out_size, void* d_ws, size_t ws_size,
                              hipStream_t stream) {
    const float* rep   = (const float*)d_in[0];
    const float* W     = (const float*)d_in[1];
    const float* bias  = (const float*)d_in[2];
    const int*   scope = (const int*)d_in[3];

    const int nsum   = in_sizes[0] / D_DIM;
    const int strips = (nsum + 31) >> 5;

    unsigned* Bfrag = (unsigned*)d_ws;                    // 393216 B
    float*    H     = (float*)((char*)d_ws + 393216);     // strips*32*128 fp32

    build_bfrag<<<48, 256, 0, stream>>>(W, Bfrag);
    h_gemm<<<strips, 512, 0, stream>>>(rep, Bfrag, H, nsum);
    bag_out<<<B_BAGS, 512, 0, stream>>>(H, bias, scope, (float*)d_out, nsum);
}

// Round 11
// 93.245 us; speedup vs baseline: 1.4765x; 1.0459x over previous
//
#include <hip/hip_runtime.h>
#include <math.h>

#define B_BAGS 512
#define N_REL  128
#define D_DIM  768

typedef __attribute__((ext_vector_type(8))) short  bf16x8;
typedef __attribute__((ext_vector_type(4))) float  f32x4;

// pack truncated-bf16 of (f0,f1) -> one uint (low short = bf16(f0))
__device__ inline unsigned pack_hi(float f0, float f1) {
    return __builtin_amdgcn_perm(__float_as_uint(f1), __float_as_uint(f0), 0x07060302u);
}
__device__ inline float trunc_res(float f) {   // f - bf16_trunc(f)
    return f - __uint_as_float(__float_as_uint(f) & 0xFFFF0000u);
}

// ---------------------------------------------------------------------------
// K1: fragment-ordered bf16 hi/lo of W (validated r2-r10).
// uint index = ((s*8 + tile)*2 + p)*256 + lane*4 + 0..3
// Element: n = tile*16 + (lane&15), k = s*32 + (lane>>4)*8 + j.
// ---------------------------------------------------------------------------
__global__ void build_bfrag(const float* __restrict__ W, unsigned* __restrict__ Bfrag) {
    int flat = blockIdx.x * 256 + threadIdx.x;     // 0..12287
    int lane = flat & 63;
    int tile = (flat >> 6) & 7;
    int s    = flat >> 9;                          // 0..23
    int n  = tile * 16 + (lane & 15);
    int k0 = s * 32 + (lane >> 4) * 8;
    const float* src = &W[n * D_DIM + k0];
    float f[8];
    #pragma unroll
    for (int j = 0; j < 8; ++j) f[j] = src[j];
    unsigned hi[4], lo[4];
    #pragma unroll
    for (int q = 0; q < 4; ++q) {
        hi[q] = pack_hi(f[2*q], f[2*q+1]);
        lo[q] = pack_hi(trunc_res(f[2*q]), trunc_res(f[2*q+1]));
    }
    unsigned base = (unsigned)(((s * 8 + tile) * 2) * 64 + lane) * 4;
    *(uint4*)&Bfrag[base]          = make_uint4(hi[0], hi[1], hi[2], hi[3]);
    *(uint4*)&Bfrag[base + 64 * 4] = make_uint4(lo[0], lo[1], lo[2], lo[3]);
}

// ---------------------------------------------------------------------------
// K2: dense H = rep @ W^T, 16-row strips x split-K/2. grid (S, 2), 256 thr
// = 4 waves; wave wv owns n-tile pair {2wv, 2wv+1}. A staged per-128-k chunk
// into LDS as packed bf16 hi/lo (stride-68 pad, 2-way = free). B direct from
// L2-resident Bfrag (validated layout). Plain stores to partial Hp[chunk].
// 8.7 KB LDS + low VGPR -> up to 8 blocks/CU; ~1054 blocks all co-resident.
// ---------------------------------------------------------------------------
__global__ __launch_bounds__(256, 8) void h_gemm(
    const float*    __restrict__ rep,
    const unsigned* __restrict__ Bfrag,
    float*          __restrict__ Hp,     // 2 buffers of hstride floats
    int nsum, int hstride)
{
    __shared__ unsigned As[2][16][68];   // [plane][row][64+4 pad]  8.7 KB

    const int t     = threadIdx.x;
    const int strip = blockIdx.x;
    const int chunk = blockIdx.y;        // K-half (12 gs each)

    const int wv   = t >> 6;             // 0..3
    const int lane = t & 63;
    const int nl15 = lane & 15;
    const int lg   = lane >> 4;

    // staging: thread covers row t>>4, 8 k-cols at (t&15)*8 of each 128-chunk
    const int srow = t >> 4;
    const int scq  = t & 15;
    int grow = strip * 16 + srow;
    grow = (grow > nsum - 1) ? (nsum - 1) : grow;
    const float* srp = &rep[(size_t)grow * D_DIM + chunk * 384 + scq * 8];

    f32x4 acc[2][2];   // [ntl][0]=hi*hi, [1]=hi*lo+lo*hi
    #pragma unroll
    for (int ntl = 0; ntl < 2; ++ntl) {
        acc[ntl][0] = f32x4{0.f, 0.f, 0.f, 0.f};
        acc[ntl][1] = f32x4{0.f, 0.f, 0.f, 0.f};
    }

    #pragma unroll
    for (int st = 0; st < 3; ++st) {
        if (st) __syncthreads();         // previous chunk's reads complete
        // ---- stage 128 k-cols: fp32 -> bf16 hi/lo into LDS ----
        {
            const float4 v0 = *(const float4*)&srp[st * 128];
            const float4 v1 = *(const float4*)&srp[st * 128 + 4];
            const float f[8] = {v0.x, v0.y, v0.z, v0.w, v1.x, v1.y, v1.z, v1.w};
            unsigned hi[4], lo[4];
            #pragma unroll
            for (int w = 0; w < 4; ++w) {
                hi[w] = pack_hi(f[2*w], f[2*w+1]);
                lo[w] = pack_hi(trunc_res(f[2*w]), trunc_res(f[2*w+1]));
            }
            *(uint4*)&As[0][srow][scq * 4] = make_uint4(hi[0], hi[1], hi[2], hi[3]);
            *(uint4*)&As[1][srow][scq * 4] = make_uint4(lo[0], lo[1], lo[2], lo[3]);
        }
        __syncthreads();

        // ---- compute 4 gs of this chunk ----
        #pragma unroll
        for (int g = 0; g < 4; ++g) {
            const int gs = chunk * 12 + st * 4 + g;       // global K-step 0..23
            const bf16x8 ah = *(const bf16x8*)&As[0][nl15][g * 16 + lg * 4];
            const bf16x8 al = *(const bf16x8*)&As[1][nl15][g * 16 + lg * 4];
            #pragma unroll
            for (int ntl = 0; ntl < 2; ++ntl) {
                const int nt = wv * 2 + ntl;
                const bf16x8 bh = *(const bf16x8*)&Bfrag[((gs * 8 + nt) * 2 + 0) * 256 + lane * 4];
                const bf16x8 bl = *(const bf16x8*)&Bfrag[((gs * 8 + nt) * 2 + 1) * 256 + lane * 4];
                acc[ntl][0] = __builtin_amdgcn_mfma_f32_16x16x32_bf16(ah, bh, acc[ntl][0], 0, 0, 0);
                acc[ntl][1] = __builtin_amdgcn_mfma_f32_16x16x32_bf16(ah, bl, acc[ntl][1], 0, 0, 0);
                acc[ntl][1] = __builtin_amdgcn_mfma_f32_16x16x32_bf16(al, bh, acc[ntl][1], 0, 0, 0);
            }
        }
    }

    // ---- epilogue: C/D layout col=lane&15, row=(lane>>4)*4+r (validated) ----
    float* H = Hp + (size_t)chunk * hstride;
    const int rowb = strip * 16 + lg * 4;
    #pragma unroll
    for (int ntl = 0; ntl < 2; ++ntl) {
        const int col = (wv * 2 + ntl) * 16 + nl15;
        #pragma unroll
        for (int r = 0; r < 4; ++r)
            H[(size_t)(rowb + r) * N_REL + col] = acc[ntl][0][r] + acc[ntl][1][r];
    }
}

// ---------------------------------------------------------------------------
// K3: per-bag output (R10 verbatim except 2-partial sum). 512 thr = 8 waves;
// wave T = wv owns n-tile T. gv loaded from the 2 Hp partials in C/D-register
// positions, then the r5-r10-validated tail: in-register masked softmax over
// m, frag scatter, 24-MFMA phase 2, in-register row softmax over k, diag.
// ---------------------------------------------------------------------------
__global__ __launch_bounds__(512, 2) void bag_out(
    const float* __restrict__ Hp, int hstride,
    const float* __restrict__ bias,
    const int*   __restrict__ scope,
    float*       __restrict__ out,
    int nsum)
{
    __shared__ unsigned Gfrag[8 * 2 * 64 * 4];    // 16 KB [tile][p][lane][4]
    __shared__ unsigned SMfrag[8 * 2 * 64 * 4];   // 16 KB

    const int t = threadIdx.x;
    const int b = blockIdx.x;
    const int start = scope[2 * b];
    const int size  = scope[2 * b + 1] - start;   // in [8, 25)

    const int wv   = t >> 6;
    const int lane = t & 63;
    const int nl15 = lane & 15;
    const int lg   = lane >> 4;
    const int T    = wv;

    // ---- gv: sum of 2 partials in C/D positions ----
    float gv[2][4], smv[2][4];
    #pragma unroll
    for (int mt = 0; mt < 2; ++mt)
        #pragma unroll
        for (int r = 0; r < 4; ++r) {
            int row = start + mt * 16 + lg * 4 + r;
            row = (row > nsum - 1) ? (nsum - 1) : row;   // pad rows: masked later
            const float* p = &Hp[(size_t)row * N_REL + T * 16 + nl15];
            gv[mt][r] = p[0] + p[(size_t)hstride];
        }

    // ---- in-register masked softmax over m (validated r5-r10) ----
    float vmax = -INFINITY;
    #pragma unroll
    for (int mt = 0; mt < 2; ++mt)
        #pragma unroll
        for (int r = 0; r < 4; ++r) {
            const int m = mt * 16 + lg * 4 + r;
            if (m < size) vmax = fmaxf(vmax, gv[mt][r]);
        }
    vmax = fmaxf(vmax, __shfl_xor(vmax, 16));
    vmax = fmaxf(vmax, __shfl_xor(vmax, 32));

    float ssum = 0.f;
    #pragma unroll
    for (int mt = 0; mt < 2; ++mt)
        #pragma unroll
        for (int r = 0; r < 4; ++r) {
            const int m = mt * 16 + lg * 4 + r;
            float e = (m < size) ? __expf(gv[mt][r] - vmax) : 0.f;
            smv[mt][r] = e;
            ssum += e;
        }
    ssum += __shfl_xor(ssum, 16);
    ssum += __shfl_xor(ssum, 32);
    const float inv = 1.f / ssum;
    #pragma unroll
    for (int mt = 0; mt < 2; ++mt)
        #pragma unroll
        for (int r = 0; r < 4; ++r) smv[mt][r] *= inv;

    // ---- scatter to frag layouts (validated r4-r10) ----
    #pragma unroll
    for (int mt = 0; mt < 2; ++mt)
        #pragma unroll
        for (int rp = 0; rp < 4; rp += 2) {
            const int m     = mt * 16 + lg * 4 + rp;
            const int lane2 = (m >> 3) * 16 + nl15;
            const int word  = (m >> 1) & 3;
            const int ihi = ((T * 2 + 0) * 64 + lane2) * 4 + word;
            const int ilo = ((T * 2 + 1) * 64 + lane2) * 4 + word;
            Gfrag[ihi]  = pack_hi(gv[mt][rp], gv[mt][rp + 1]);
            Gfrag[ilo]  = pack_hi(trunc_res(gv[mt][rp]), trunc_res(gv[mt][rp + 1]));
            SMfrag[ihi] = pack_hi(smv[mt][rp], smv[mt][rp + 1]);
            SMfrag[ilo] = pack_hi(trunc_res(smv[mt][rp]), trunc_res(smv[mt][rp + 1]));
        }
    __syncthreads();   // the only barrier

    // ---- Phase 2: row-tile T of full = SM @ G (validated r6-r10) ----
    float bias_r[8];
    #pragma unroll
    for (int ct = 0; ct < 8; ++ct) bias_r[ct] = bias[ct * 16 + nl15];

    f32x4 facc[8];
    #pragma unroll
    for (int ct = 0; ct < 8; ++ct) facc[ct] = f32x4{0.f, 0.f, 0.f, 0.f};

    const bf16x8 ah2 = *(const bf16x8*)&SMfrag[((T * 2 + 0) * 64 + lane) * 4];
    const bf16x8 al2 = *(const bf16x8*)&SMfrag[((T * 2 + 1) * 64 + lane) * 4];
    #pragma unroll
    for (int ct = 0; ct < 8; ++ct) {
        const bf16x8 bh = *(const bf16x8*)&Gfrag[((ct * 2 + 0) * 64 + lane) * 4];
        const bf16x8 bl = *(const bf16x8*)&Gfrag[((ct * 2 + 1) * 64 + lane) * 4];
        facc[ct] = __builtin_amdgcn_mfma_f32_16x16x32_bf16(ah2, bh, facc[ct], 0, 0, 0);
        facc[ct] = __builtin_amdgcn_mfma_f32_16x16x32_bf16(ah2, bl, facc[ct], 0, 0, 0);
        facc[ct] = __builtin_amdgcn_mfma_f32_16x16x32_bf16(al2, bh, facc[ct], 0, 0, 0);
    }

    // ---- in-register row softmax over k + diagonal -> out (validated) ----
    #pragma unroll
    for (int r = 0; r < 4; ++r) {
        float s[8];
        #pragma unroll
        for (int ct = 0; ct < 8; ++ct) s[ct] = facc[ct][r] + bias_r[ct];

        float mx = s[0];
        #pragma unroll
        for (int ct = 1; ct < 8; ++ct) mx = fmaxf(mx, s[ct]);
        mx = fmaxf(mx, __shfl_xor(mx, 1));
        mx = fmaxf(mx, __shfl_xor(mx, 2));
        mx = fmaxf(mx, __shfl_xor(mx, 4));
        mx = fmaxf(mx, __shfl_xor(mx, 8));

        float l = 0.f;
        #pragma unroll
        for (int ct = 0; ct < 8; ++ct) l += __expf(s[ct] - mx);
        l += __shfl_xor(l, 1);
        l += __shfl_xor(l, 2);
        l += __shfl_xor(l, 4);
        l += __shfl_xor(l, 8);

        const int nl = lg * 4 + r;
        float sd = s[0];
        #pragma unroll
        for (int ct = 1; ct < 8; ++ct) sd = (ct == T) ? s[ct] : sd;
        if (nl15 == nl) {
            out[b * N_REL + T * 16 + nl] = __expf(sd - mx) / l;
        }
    }
}

// ---------------------------------------------------------------------------
extern "C" void kernel_launch(void* const* d_in, const int* in_sizes, int n_in,
                              void* d_out, int out_size, void* d_ws, size_t ws_size,
                              hipStream_t stream) {
    const float* rep   = (const float*)d_in[0];
    const float* W     = (const float*)d_in[1];
    const float* bias  = (const float*)d_in[2];
    const int*   scope = (const int*)d_in[3];

    const int nsum    = in_sizes[0] / D_DIM;
    const int strips  = (nsum + 15) >> 4;
    const int hstride = strips * 16 * N_REL;    // floats per partial buffer

    unsigned* Bfrag = (unsigned*)d_ws;                    // 393216 B
    float*    Hp    = (float*)((char*)d_ws + 393216);     // 2 * hstride fp32

    build_bfrag<<<48, 256, 0, stream>>>(W, Bfrag);
    h_gemm<<<dim3(strips, 2), 256, 0, stream>>>(rep, Bfrag, Hp, nsum, hstride);
    bag_out<<<B_BAGS, 512, 0, stream>>>(Hp, hstride, bias, scope,
                                        (float*)d_out, nsum);
}